// Round 1
// baseline (943.007 us; speedup 1.0000x reference)
//
#include <hip/hip_runtime.h>
#include <math.h>

// ---------------------------------------------------------------------------
// PermutedNetwork: 3x (offset-conv3x3 -> deform_conv3x3 -> relu [-> maxpool2])
// then adaptive-avgpool(3x3) -> fc(576->10).
// fp32 throughout (no fp32 MFMA on CDNA4; vector ALU).
// ---------------------------------------------------------------------------

// Generic 3x3 conv, stride 1, pad 1, NCHW/OIHW. One thread per output elem.
__global__ void conv3x3_kernel(const float* __restrict__ in, const float* __restrict__ w,
                               const float* __restrict__ bias, float* __restrict__ out,
                               int B, int Cin, int Cout, int H, int W) {
  int gid = blockIdx.x * blockDim.x + threadIdx.x;
  int total = B * Cout * H * W;
  if (gid >= total) return;
  int x = gid % W;
  int t = gid / W;
  int y = t % H; t /= H;
  int o = t % Cout;
  int b = t / Cout;
  float acc = bias[o];
  const float* inb = in + (size_t)(b * Cin) * H * W;
  const float* wo  = w + (size_t)o * Cin * 9;
  for (int c = 0; c < Cin; ++c) {
    const float* inp = inb + (size_t)c * H * W;
    const float* wp  = wo + c * 9;
#pragma unroll
    for (int ky = 0; ky < 3; ++ky) {
      int yy = y + ky - 1;
      if (yy < 0 || yy >= H) continue;
#pragma unroll
      for (int kx = 0; kx < 3; ++kx) {
        int xx = x + kx - 1;
        if (xx < 0 || xx >= W) continue;
        acc = fmaf(wp[ky * 3 + kx], inp[yy * W + xx], acc);
      }
    }
  }
  out[gid] = acc;
}

// Deformable 3x3 conv (torchvision semantics: zero outside, bilinear), + ReLU.
// One thread per (b, y, x); computes all COUT output channels so the bilinear
// gathers are shared across output channels.
// If FUSE_OFF: computes the 18-channel offset conv inline from x (layer 1).
template <int CIN, int COUT, bool FUSE_OFF>
__global__ void deform_kernel(const float* __restrict__ x,      // [B,CIN,H,W]
                              const float* __restrict__ off_in, // [B,18,H,W] (if !FUSE_OFF)
                              const float* __restrict__ woff,   // [18,CIN,3,3] (if FUSE_OFF)
                              const float* __restrict__ boff,   // [18]
                              const float* __restrict__ w,      // [COUT,CIN,3,3]
                              const float* __restrict__ bias,   // [COUT]
                              float* __restrict__ out,          // [B,COUT,H,W]
                              int B, int H, int W) {
  int gid = blockIdx.x * blockDim.x + threadIdx.x;
  if (gid >= B * H * W) return;
  int xi = gid % W;
  int t = gid / W;
  int yi = t % H;
  int b = t / H;

  const float* xb = x + (size_t)b * CIN * H * W;

  float off[18];
  if constexpr (FUSE_OFF) {
#pragma unroll
    for (int tc = 0; tc < 18; ++tc) off[tc] = boff[tc];
    for (int c = 0; c < CIN; ++c) {
      const float* inp = xb + (size_t)c * H * W;
#pragma unroll
      for (int ky = 0; ky < 3; ++ky) {
        int yy = yi + ky - 1;
        if (yy < 0 || yy >= H) continue;
#pragma unroll
        for (int kx = 0; kx < 3; ++kx) {
          int xx = xi + kx - 1;
          if (xx < 0 || xx >= W) continue;
          float v = inp[yy * W + xx];
#pragma unroll
          for (int tc = 0; tc < 18; ++tc)
            off[tc] = fmaf(woff[(tc * CIN + c) * 9 + ky * 3 + kx], v, off[tc]);
        }
      }
    }
  } else {
    const float* op = off_in + (size_t)b * 18 * H * W + (size_t)yi * W + xi;
#pragma unroll
    for (int tc = 0; tc < 18; ++tc) off[tc] = op[(size_t)tc * H * W];
  }

  float acc[COUT];
#pragma unroll
  for (int o = 0; o < COUT; ++o) acc[o] = bias[o];

#pragma unroll
  for (int k = 0; k < 9; ++k) {
    float py = (float)yi + (float)(k / 3 - 1) + off[2 * k];
    float px = (float)xi + (float)(k % 3 - 1) + off[2 * k + 1];
    float y0f = floorf(py), x0f = floorf(px);
    float fy = py - y0f, fx = px - x0f;
    int y0 = (int)y0f, x0 = (int)x0f;
    int y1 = y0 + 1, x1 = x0 + 1;
    float vy0 = (y0 >= 0 && y0 < H) ? 1.f : 0.f;
    float vy1 = (y1 >= 0 && y1 < H) ? 1.f : 0.f;
    float vx0 = (x0 >= 0 && x0 < W) ? 1.f : 0.f;
    float vx1 = (x1 >= 0 && x1 < W) ? 1.f : 0.f;
    float w00 = (1.f - fy) * (1.f - fx) * vy0 * vx0;
    float w01 = (1.f - fy) * fx * vy0 * vx1;
    float w10 = fy * (1.f - fx) * vy1 * vx0;
    float w11 = fy * fx * vy1 * vx1;
    int cy0 = min(max(y0, 0), H - 1), cy1 = min(max(y1, 0), H - 1);
    int cx0 = min(max(x0, 0), W - 1), cx1 = min(max(x1, 0), W - 1);
    int i00 = cy0 * W + cx0, i01 = cy0 * W + cx1;
    int i10 = cy1 * W + cx0, i11 = cy1 * W + cx1;
    for (int c = 0; c < CIN; ++c) {
      const float* ic = xb + (size_t)c * H * W;
      float val = w00 * ic[i00] + w01 * ic[i01] + w10 * ic[i10] + w11 * ic[i11];
#pragma unroll
      for (int o = 0; o < COUT; ++o)
        acc[o] = fmaf(w[(o * CIN + c) * 9 + k], val, acc[o]);
    }
  }

  float* op = out + (size_t)b * COUT * H * W + (size_t)yi * W + xi;
#pragma unroll
  for (int o = 0; o < COUT; ++o)
    op[(size_t)o * H * W] = fmaxf(acc[o], 0.f);
}

// 2x2 stride-2 max pool.
__global__ void maxpool2_kernel(const float* __restrict__ in, float* __restrict__ out,
                                int B, int C, int H, int W) {
  int Ho = H / 2, Wo = W / 2;
  int gid = blockIdx.x * blockDim.x + threadIdx.x;
  int total = B * C * Ho * Wo;
  if (gid >= total) return;
  int x = gid % Wo;
  int t = gid / Wo;
  int y = t % Ho; t /= Ho;
  int c = t % C;
  int b = t / C;
  const float* p = in + ((size_t)(b * C + c) * H + 2 * y) * W + 2 * x;
  out[gid] = fmaxf(fmaxf(p[0], p[1]), fmaxf(p[W], p[W + 1]));
}

// Adaptive avg pool 24->3 (8x8 bins) + flatten + fc(576->10). Block per batch.
__global__ void poolfc_kernel(const float* __restrict__ h,   // [B,64,24,24]
                              const float* __restrict__ wfc, // [10,576]
                              const float* __restrict__ bfc, // [10]
                              float* __restrict__ out) {     // [B,10]
  __shared__ float feat[576];
  int b = blockIdx.x;
  int f = threadIdx.x; // 576 threads
  int c = f / 9, ij = f % 9, i = ij / 3, j = ij % 3;
  const float* p = h + ((size_t)(b * 64 + c) * 24 + i * 8) * 24 + j * 8;
  float s = 0.f;
#pragma unroll
  for (int r = 0; r < 8; ++r)
#pragma unroll
    for (int q = 0; q < 8; ++q)
      s += p[r * 24 + q];
  feat[f] = s * (1.f / 64.f);
  __syncthreads();
  if (f < 10) {
    float acc = bfc[f];
    const float* wp = wfc + f * 576;
    for (int t = 0; t < 576; ++t) acc = fmaf(wp[t], feat[t], acc);
    out[b * 10 + f] = acc;
  }
}

extern "C" void kernel_launch(void* const* d_in, const int* in_sizes, int n_in,
                              void* d_out, int out_size, void* d_ws, size_t ws_size,
                              hipStream_t stream) {
  const float* x      = (const float*)d_in[0];
  const float* w_off1 = (const float*)d_in[1];
  const float* b_off1 = (const float*)d_in[2];
  const float* w1     = (const float*)d_in[3];
  const float* b1     = (const float*)d_in[4];
  const float* w_off2 = (const float*)d_in[5];
  const float* b_off2 = (const float*)d_in[6];
  const float* w2     = (const float*)d_in[7];
  const float* b2     = (const float*)d_in[8];
  const float* w_off3 = (const float*)d_in[9];
  const float* b_off3 = (const float*)d_in[10];
  const float* w3     = (const float*)d_in[11];
  const float* b3     = (const float*)d_in[12];
  const float* w_fc   = (const float*)d_in[13];
  const float* b_fc   = (const float*)d_in[14];
  float* out = (float*)d_out;

  char* ws = (char*)d_ws;
  // Region A: h buffers (max 64*16*96*96*4 = 37,748,736 B)
  // Region B: pooled h  (max 64*16*48*48*4 =  9,437,184 B)
  // Region C: offsets   (max 64*18*48*48*4 = 10,616,832 B)
  float* A  = (float*)(ws);
  float* Bp = (float*)(ws + 37748736);
  float* Cp = (float*)(ws + 47185920);

  const int thr = 256;

  // ---- Layer 1: fused offset-conv + deform + relu: x[64,1,96,96] -> A[64,16,96,96]
  {
    int total = 64 * 96 * 96;
    deform_kernel<1, 16, true><<<(total + thr - 1) / thr, thr, 0, stream>>>(
        x, nullptr, w_off1, b_off1, w1, b1, A, 64, 96, 96);
  }
  // maxpool -> Bp[64,16,48,48]
  {
    int total = 64 * 16 * 48 * 48;
    maxpool2_kernel<<<(total + thr - 1) / thr, thr, 0, stream>>>(A, Bp, 64, 16, 96, 96);
  }

  // ---- Layer 2: offset conv Bp -> Cp[64,18,48,48]
  {
    int total = 64 * 18 * 48 * 48;
    conv3x3_kernel<<<(total + thr - 1) / thr, thr, 0, stream>>>(Bp, w_off2, b_off2, Cp,
                                                               64, 16, 18, 48, 48);
  }
  // deform + relu -> A[64,32,48,48]
  {
    int total = 64 * 48 * 48;
    deform_kernel<16, 32, false><<<(total + thr - 1) / thr, thr, 0, stream>>>(
        Bp, Cp, nullptr, nullptr, w2, b2, A, 64, 48, 48);
  }
  // maxpool -> Bp[64,32,24,24]
  {
    int total = 64 * 32 * 24 * 24;
    maxpool2_kernel<<<(total + thr - 1) / thr, thr, 0, stream>>>(A, Bp, 64, 32, 48, 48);
  }

  // ---- Layer 3: offset conv Bp -> Cp[64,18,24,24]
  {
    int total = 64 * 18 * 24 * 24;
    conv3x3_kernel<<<(total + thr - 1) / thr, thr, 0, stream>>>(Bp, w_off3, b_off3, Cp,
                                                               64, 32, 18, 24, 24);
  }
  // deform + relu -> A[64,64,24,24]
  {
    int total = 64 * 24 * 24;
    deform_kernel<32, 64, false><<<(total + thr - 1) / thr, thr, 0, stream>>>(
        Bp, Cp, nullptr, nullptr, w3, b3, A, 64, 24, 24);
  }

  // ---- avgpool(3x3) + fc -> out[64,10]
  poolfc_kernel<<<64, 576, 0, stream>>>(A, w_fc, b_fc, out);
}

// Round 2
// 594.863 us; speedup vs baseline: 1.5853x; 1.5853x over previous
//
#include <hip/hip_runtime.h>
#include <math.h>

// ---------------------------------------------------------------------------
// PermutedNetwork: 3x (offset-conv3x3 -> deform_conv3x3 -> relu [-> maxpool2])
// then adaptive-avgpool(3x3) -> fc(576->10).
// fp32 throughout (no fp32 MFMA on CDNA4; vector ALU).
//
// R2: split COUT across blockIdx.y (NSPLIT) so acc[] stays <=16 floats.
//     Fixes layer-3 register spill (acc[64] -> scratch) + 144-block grid.
// ---------------------------------------------------------------------------

// Generic 3x3 conv, stride 1, pad 1, NCHW/OIHW. One thread per output elem.
__global__ void conv3x3_kernel(const float* __restrict__ in, const float* __restrict__ w,
                               const float* __restrict__ bias, float* __restrict__ out,
                               int B, int Cin, int Cout, int H, int W) {
  int gid = blockIdx.x * blockDim.x + threadIdx.x;
  int total = B * Cout * H * W;
  if (gid >= total) return;
  int x = gid % W;
  int t = gid / W;
  int y = t % H; t /= H;
  int o = t % Cout;
  int b = t / Cout;
  float acc = bias[o];
  const float* inb = in + (size_t)(b * Cin) * H * W;
  const float* wo  = w + (size_t)o * Cin * 9;
  for (int c = 0; c < Cin; ++c) {
    const float* inp = inb + (size_t)c * H * W;
    const float* wp  = wo + c * 9;
#pragma unroll
    for (int ky = 0; ky < 3; ++ky) {
      int yy = y + ky - 1;
      if (yy < 0 || yy >= H) continue;
#pragma unroll
      for (int kx = 0; kx < 3; ++kx) {
        int xx = x + kx - 1;
        if (xx < 0 || xx >= W) continue;
        acc = fmaf(wp[ky * 3 + kx], inp[yy * W + xx], acc);
      }
    }
  }
  out[gid] = acc;
}

// Deformable 3x3 conv (torchvision semantics: zero outside, bilinear), + ReLU.
// Thread per (b, y, x); blockIdx.y selects a group of COUT/NSPLIT output
// channels, so the accumulator array stays small (<=16) and never spills.
// If FUSE_OFF: computes the 18-channel offset conv inline from x (layer 1).
template <int CIN, int COUT, int NSPLIT, bool FUSE_OFF>
__global__ void deform_kernel(const float* __restrict__ x,      // [B,CIN,H,W]
                              const float* __restrict__ off_in, // [B,18,H,W] (if !FUSE_OFF)
                              const float* __restrict__ woff,   // [18,CIN,3,3] (if FUSE_OFF)
                              const float* __restrict__ boff,   // [18]
                              const float* __restrict__ w,      // [COUT,CIN,3,3]
                              const float* __restrict__ bias,   // [COUT]
                              float* __restrict__ out,          // [B,COUT,H,W]
                              int B, int H, int W) {
  constexpr int OC = COUT / NSPLIT;  // channels this thread accumulates
  int gid = blockIdx.x * blockDim.x + threadIdx.x;
  if (gid >= B * H * W) return;
  int xi = gid % W;
  int t = gid / W;
  int yi = t % H;
  int b = t / H;
  int og = blockIdx.y;               // output-channel group
  int obase = og * OC;

  const float* xb = x + (size_t)b * CIN * H * W;

  float off[18];
  if constexpr (FUSE_OFF) {
#pragma unroll
    for (int tc = 0; tc < 18; ++tc) off[tc] = boff[tc];
    for (int c = 0; c < CIN; ++c) {
      const float* inp = xb + (size_t)c * H * W;
#pragma unroll
      for (int ky = 0; ky < 3; ++ky) {
        int yy = yi + ky - 1;
        if (yy < 0 || yy >= H) continue;
#pragma unroll
        for (int kx = 0; kx < 3; ++kx) {
          int xx = xi + kx - 1;
          if (xx < 0 || xx >= W) continue;
          float v = inp[yy * W + xx];
#pragma unroll
          for (int tc = 0; tc < 18; ++tc)
            off[tc] = fmaf(woff[(tc * CIN + c) * 9 + ky * 3 + kx], v, off[tc]);
        }
      }
    }
  } else {
    const float* op = off_in + (size_t)b * 18 * H * W + (size_t)yi * W + xi;
#pragma unroll
    for (int tc = 0; tc < 18; ++tc) off[tc] = op[(size_t)tc * H * W];
  }

  float acc[OC];
#pragma unroll
  for (int o = 0; o < OC; ++o) acc[o] = bias[obase + o];

#pragma unroll
  for (int k = 0; k < 9; ++k) {
    float py = (float)yi + (float)(k / 3 - 1) + off[2 * k];
    float px = (float)xi + (float)(k % 3 - 1) + off[2 * k + 1];
    float y0f = floorf(py), x0f = floorf(px);
    float fy = py - y0f, fx = px - x0f;
    int y0 = (int)y0f, x0 = (int)x0f;
    int y1 = y0 + 1, x1 = x0 + 1;
    float vy0 = (y0 >= 0 && y0 < H) ? 1.f : 0.f;
    float vy1 = (y1 >= 0 && y1 < H) ? 1.f : 0.f;
    float vx0 = (x0 >= 0 && x0 < W) ? 1.f : 0.f;
    float vx1 = (x1 >= 0 && x1 < W) ? 1.f : 0.f;
    float w00 = (1.f - fy) * (1.f - fx) * vy0 * vx0;
    float w01 = (1.f - fy) * fx * vy0 * vx1;
    float w10 = fy * (1.f - fx) * vy1 * vx0;
    float w11 = fy * fx * vy1 * vx1;
    int cy0 = min(max(y0, 0), H - 1), cy1 = min(max(y1, 0), H - 1);
    int cx0 = min(max(x0, 0), W - 1), cx1 = min(max(x1, 0), W - 1);
    int i00 = cy0 * W + cx0, i01 = cy0 * W + cx1;
    int i10 = cy1 * W + cx0, i11 = cy1 * W + cx1;
    for (int c = 0; c < CIN; ++c) {
      const float* ic = xb + (size_t)c * H * W;
      float val = w00 * ic[i00] + w01 * ic[i01] + w10 * ic[i10] + w11 * ic[i11];
#pragma unroll
      for (int o = 0; o < OC; ++o)
        acc[o] = fmaf(w[((obase + o) * CIN + c) * 9 + k], val, acc[o]);
    }
  }

  float* op = out + (size_t)b * COUT * H * W + (size_t)obase * H * W + (size_t)yi * W + xi;
#pragma unroll
  for (int o = 0; o < OC; ++o)
    op[(size_t)o * H * W] = fmaxf(acc[o], 0.f);
}

// 2x2 stride-2 max pool.
__global__ void maxpool2_kernel(const float* __restrict__ in, float* __restrict__ out,
                                int B, int C, int H, int W) {
  int Ho = H / 2, Wo = W / 2;
  int gid = blockIdx.x * blockDim.x + threadIdx.x;
  int total = B * C * Ho * Wo;
  if (gid >= total) return;
  int x = gid % Wo;
  int t = gid / Wo;
  int y = t % Ho; t /= Ho;
  int c = t % C;
  int b = t / C;
  const float* p = in + ((size_t)(b * C + c) * H + 2 * y) * W + 2 * x;
  out[gid] = fmaxf(fmaxf(p[0], p[1]), fmaxf(p[W], p[W + 1]));
}

// Adaptive avg pool 24->3 (8x8 bins) + flatten + fc(576->10). Block per batch.
__global__ void poolfc_kernel(const float* __restrict__ h,   // [B,64,24,24]
                              const float* __restrict__ wfc, // [10,576]
                              const float* __restrict__ bfc, // [10]
                              float* __restrict__ out) {     // [B,10]
  __shared__ float feat[576];
  int b = blockIdx.x;
  int f = threadIdx.x; // 576 threads
  int c = f / 9, ij = f % 9, i = ij / 3, j = ij % 3;
  const float* p = h + ((size_t)(b * 64 + c) * 24 + i * 8) * 24 + j * 8;
  float s = 0.f;
#pragma unroll
  for (int r = 0; r < 8; ++r)
#pragma unroll
    for (int q = 0; q < 8; ++q)
      s += p[r * 24 + q];
  feat[f] = s * (1.f / 64.f);
  __syncthreads();
  if (f < 10) {
    float acc = bfc[f];
    const float* wp = wfc + f * 576;
    for (int t = 0; t < 576; ++t) acc = fmaf(wp[t], feat[t], acc);
    out[b * 10 + f] = acc;
  }
}

extern "C" void kernel_launch(void* const* d_in, const int* in_sizes, int n_in,
                              void* d_out, int out_size, void* d_ws, size_t ws_size,
                              hipStream_t stream) {
  const float* x      = (const float*)d_in[0];
  const float* w_off1 = (const float*)d_in[1];
  const float* b_off1 = (const float*)d_in[2];
  const float* w1     = (const float*)d_in[3];
  const float* b1     = (const float*)d_in[4];
  const float* w_off2 = (const float*)d_in[5];
  const float* b_off2 = (const float*)d_in[6];
  const float* w2     = (const float*)d_in[7];
  const float* b2     = (const float*)d_in[8];
  const float* w_off3 = (const float*)d_in[9];
  const float* b_off3 = (const float*)d_in[10];
  const float* w3     = (const float*)d_in[11];
  const float* b3     = (const float*)d_in[12];
  const float* w_fc   = (const float*)d_in[13];
  const float* b_fc   = (const float*)d_in[14];
  float* out = (float*)d_out;

  char* ws = (char*)d_ws;
  float* A  = (float*)(ws);               // up to 37.75 MB
  float* Bp = (float*)(ws + 37748736);    // up to 9.44 MB
  float* Cp = (float*)(ws + 47185920);    // up to 10.62 MB

  const int thr = 256;

  // ---- Layer 1: fused offset-conv + deform + relu: x[64,1,96,96] -> A[64,16,96,96]
  {
    int total = 64 * 96 * 96;
    dim3 grid((total + thr - 1) / thr, 1);
    deform_kernel<1, 16, 1, true><<<grid, thr, 0, stream>>>(
        x, nullptr, w_off1, b_off1, w1, b1, A, 64, 96, 96);
  }
  // maxpool -> Bp[64,16,48,48]
  {
    int total = 64 * 16 * 48 * 48;
    maxpool2_kernel<<<(total + thr - 1) / thr, thr, 0, stream>>>(A, Bp, 64, 16, 96, 96);
  }

  // ---- Layer 2: offset conv Bp -> Cp[64,18,48,48]
  {
    int total = 64 * 18 * 48 * 48;
    conv3x3_kernel<<<(total + thr - 1) / thr, thr, 0, stream>>>(Bp, w_off2, b_off2, Cp,
                                                               64, 16, 18, 48, 48);
  }
  // deform + relu -> A[64,32,48,48]   (NSPLIT=2 -> acc[16], 1152 blocks)
  {
    int total = 64 * 48 * 48;
    dim3 grid((total + thr - 1) / thr, 2);
    deform_kernel<16, 32, 2, false><<<grid, thr, 0, stream>>>(
        Bp, Cp, nullptr, nullptr, w2, b2, A, 64, 48, 48);
  }
  // maxpool -> Bp[64,32,24,24]
  {
    int total = 64 * 32 * 24 * 24;
    maxpool2_kernel<<<(total + thr - 1) / thr, thr, 0, stream>>>(A, Bp, 64, 32, 48, 48);
  }

  // ---- Layer 3: offset conv Bp -> Cp[64,18,24,24]
  {
    int total = 64 * 18 * 24 * 24;
    conv3x3_kernel<<<(total + thr - 1) / thr, thr, 0, stream>>>(Bp, w_off3, b_off3, Cp,
                                                               64, 32, 18, 24, 24);
  }
  // deform + relu -> A[64,64,24,24]   (NSPLIT=4 -> acc[16], 576 blocks)
  {
    int total = 64 * 24 * 24;
    dim3 grid((total + thr - 1) / thr, 4);
    deform_kernel<32, 64, 4, false><<<grid, thr, 0, stream>>>(
        Bp, Cp, nullptr, nullptr, w3, b3, A, 64, 24, 24);
  }

  // ---- avgpool(3x3) + fc -> out[64,10]
  poolfc_kernel<<<64, 576, 0, stream>>>(A, w_fc, b_fc, out);
}

// Round 3
// 395.653 us; speedup vs baseline: 2.3834x; 1.5035x over previous
//
#include <hip/hip_runtime.h>
#include <math.h>

// ---------------------------------------------------------------------------
// PermutedNetwork: 3x (offset-conv3x3 -> deform_conv3x3 -> relu [-> maxpool2])
// then adaptive-avgpool(3x3) -> fc(576->10). fp32 (no fp32 MFMA on CDNA4).
//
// R3: latency attack on the deform kernels (were 3x180us @ VALUBusy 11%):
//   - batch 24 independent gather loads before FMAs (MLP ~24, needs VGPRs ->
//     __launch_bounds__(256,4) allows up to 128)
//   - weights staged in LDS [k][c][o], broadcast float4 reads
//   - layer-3 NSPLIT=8 (1152 blocks, 4.5 waves/SIMD)
//   - conv3x3 computes all Cout per thread (patch loaded once, LDS weights)
// ---------------------------------------------------------------------------

// Generic 3x3 conv (no activation), thread per (b,y,x), all OC channels.
template <int CIN, int COUT, int NSPLIT>
__global__ __launch_bounds__(256, 4)
void conv3x3_all(const float* __restrict__ in, const float* __restrict__ w,
                 const float* __restrict__ bias, float* __restrict__ out,
                 int B, int H, int W) {
  constexpr int OC = COUT / NSPLIT;
  __shared__ float ws[9 * CIN * OC];
  int obase = blockIdx.y * OC;
  for (int t = threadIdx.x; t < 9 * CIN * OC; t += 256) {
    int k = t / (CIN * OC); int r = t % (CIN * OC);
    int c = r / OC; int o = r % OC;
    ws[t] = w[((obase + o) * CIN + c) * 9 + k];
  }
  __syncthreads();

  int gid = blockIdx.x * blockDim.x + threadIdx.x;
  if (gid >= B * H * W) return;
  int x = gid % W;
  int t0 = gid / W;
  int y = t0 % H;
  int b = t0 / H;
  int HW = H * W;
  const float* inb = in + (size_t)b * CIN * HW;

  float acc[OC];
#pragma unroll
  for (int o = 0; o < OC; ++o) acc[o] = bias[obase + o];

  int yy[3], xx[3]; float my[3], mx[3];
#pragma unroll
  for (int i = 0; i < 3; ++i) {
    int Y = y + i - 1; my[i] = (Y >= 0 && Y < H) ? 1.f : 0.f; yy[i] = min(max(Y, 0), H - 1);
    int X = x + i - 1; mx[i] = (X >= 0 && X < W) ? 1.f : 0.f; xx[i] = min(max(X, 0), W - 1);
  }

#pragma unroll 4
  for (int c = 0; c < CIN; ++c) {
    const float* ic = inb + (size_t)c * HW;
    float p[9];
#pragma unroll
    for (int ky = 0; ky < 3; ++ky)
#pragma unroll
      for (int kx = 0; kx < 3; ++kx)
        p[ky * 3 + kx] = ic[yy[ky] * W + xx[kx]] * (my[ky] * mx[kx]);
#pragma unroll
    for (int k = 0; k < 9; ++k) {
      const float* wrow = &ws[(k * CIN + c) * OC];
#pragma unroll
      for (int o = 0; o < OC; ++o) acc[o] = fmaf(wrow[o], p[k], acc[o]);
    }
  }

  float* op = out + (size_t)b * COUT * HW + (size_t)obase * HW + (size_t)y * W + x;
#pragma unroll
  for (int o = 0; o < OC; ++o) op[(size_t)o * HW] = acc[o];  // no activation
}

// Deformable 3x3 conv + ReLU. Thread per (b,y,x), OC = COUT/NSPLIT channels.
// Gathers batched: per tap-row, 3 taps x 4 corners x CC channels loaded before
// use. Weights in LDS [k][c][o] (OC multiple of 4 -> float4 broadcast reads).
template <int CIN, int COUT, int NSPLIT, bool FUSE_OFF>
__global__ __launch_bounds__(256, 4)
void deform_kernel(const float* __restrict__ x,      // [B,CIN,H,W]
                   const float* __restrict__ off_in, // [B,18,H,W] (if !FUSE_OFF)
                   const float* __restrict__ woff,   // [18,CIN,3,3] (if FUSE_OFF)
                   const float* __restrict__ boff,   // [18]
                   const float* __restrict__ w,      // [COUT,CIN,3,3]
                   const float* __restrict__ bias,   // [COUT]
                   float* __restrict__ out,          // [B,COUT,H,W]
                   int B, int H, int W) {
  constexpr int OC = COUT / NSPLIT;
  __shared__ __align__(16) float ws[9 * CIN * OC];
  __shared__ __align__(16) float wos[FUSE_OFF ? 9 * CIN * 18 : 1];

  int obase = blockIdx.y * OC;
  for (int t = threadIdx.x; t < 9 * CIN * OC; t += 256) {
    int k = t / (CIN * OC); int r = t % (CIN * OC);
    int c = r / OC; int o = r % OC;
    ws[t] = w[((obase + o) * CIN + c) * 9 + k];
  }
  if constexpr (FUSE_OFF) {
    for (int t = threadIdx.x; t < 9 * CIN * 18; t += 256) {
      int k = t / (CIN * 18); int r = t % (CIN * 18);
      int c = r / 18; int tc = r % 18;
      wos[t] = woff[(tc * CIN + c) * 9 + k];
    }
  }
  __syncthreads();

  int gid = blockIdx.x * blockDim.x + threadIdx.x;
  if (gid >= B * H * W) return;
  int xi = gid % W;
  int t0 = gid / W;
  int yi = t0 % H;
  int b = t0 / H;
  int HW = H * W;
  const float* xb = x + (size_t)b * CIN * HW;

  float off[18];
  if constexpr (FUSE_OFF) {
#pragma unroll
    for (int tc = 0; tc < 18; ++tc) off[tc] = boff[tc];
#pragma unroll
    for (int c = 0; c < CIN; ++c) {
      const float* inp = xb + (size_t)c * HW;
#pragma unroll
      for (int ky = 0; ky < 3; ++ky) {
        int yy = yi + ky - 1;
#pragma unroll
        for (int kx = 0; kx < 3; ++kx) {
          int xx = xi + kx - 1;
          float m = (yy >= 0 && yy < H && xx >= 0 && xx < W) ? 1.f : 0.f;
          int cy = min(max(yy, 0), H - 1), cx = min(max(xx, 0), W - 1);
          float v = inp[cy * W + cx] * m;
          const float2* wv = (const float2*)&wos[((ky * 3 + kx) * CIN + c) * 18];
#pragma unroll
          for (int tt = 0; tt < 9; ++tt) {
            float2 ww = wv[tt];
            off[2 * tt]     = fmaf(ww.x, v, off[2 * tt]);
            off[2 * tt + 1] = fmaf(ww.y, v, off[2 * tt + 1]);
          }
        }
      }
    }
  } else {
    const float* op = off_in + (size_t)b * 18 * HW + (size_t)yi * W + xi;
#pragma unroll
    for (int tc = 0; tc < 18; ++tc) off[tc] = op[(size_t)tc * HW];
  }

  float acc[OC];
#pragma unroll
  for (int o = 0; o < OC; ++o) acc[o] = bias[obase + o];

  constexpr int CC = (CIN >= 2) ? 2 : 1;  // channels per load batch
#pragma unroll
  for (int kg = 0; kg < 3; ++kg) {        // tap row (ky = kg)
    int idxs[3][4]; float wg[3][4];
#pragma unroll
    for (int j = 0; j < 3; ++j) {
      int k = kg * 3 + j;
      float py = (float)(yi + kg - 1) + off[2 * k];
      float px = (float)(xi + j - 1) + off[2 * k + 1];
      float y0f = floorf(py), x0f = floorf(px);
      float fy = py - y0f, fx = px - x0f;
      int y0 = (int)y0f, x0 = (int)x0f;
      int y1 = y0 + 1, x1 = x0 + 1;
      float vy0 = (y0 >= 0 && y0 < H) ? 1.f : 0.f;
      float vy1 = (y1 >= 0 && y1 < H) ? 1.f : 0.f;
      float vx0 = (x0 >= 0 && x0 < W) ? 1.f : 0.f;
      float vx1 = (x1 >= 0 && x1 < W) ? 1.f : 0.f;
      wg[j][0] = (1.f - fy) * (1.f - fx) * vy0 * vx0;
      wg[j][1] = (1.f - fy) * fx * vy0 * vx1;
      wg[j][2] = fy * (1.f - fx) * vy1 * vx0;
      wg[j][3] = fy * fx * vy1 * vx1;
      int cy0 = min(max(y0, 0), H - 1), cy1 = min(max(y1, 0), H - 1);
      int cx0 = min(max(x0, 0), W - 1), cx1 = min(max(x1, 0), W - 1);
      idxs[j][0] = cy0 * W + cx0; idxs[j][1] = cy0 * W + cx1;
      idxs[j][2] = cy1 * W + cx0; idxs[j][3] = cy1 * W + cx1;
    }
    for (int c0 = 0; c0 < CIN; c0 += CC) {
      float v[CC][3][4];
#pragma unroll
      for (int cc = 0; cc < CC; ++cc) {
        const float* ic = xb + (size_t)(c0 + cc) * HW;
#pragma unroll
        for (int j = 0; j < 3; ++j)
#pragma unroll
          for (int q = 0; q < 4; ++q) v[cc][j][q] = ic[idxs[j][q]];
      }
#pragma unroll
      for (int cc = 0; cc < CC; ++cc)
#pragma unroll
        for (int j = 0; j < 3; ++j) {
          float val = wg[j][0] * v[cc][j][0] + wg[j][1] * v[cc][j][1]
                    + wg[j][2] * v[cc][j][2] + wg[j][3] * v[cc][j][3];
          int k = kg * 3 + j;
          const float4* wv = (const float4*)&ws[(k * CIN + (c0 + cc)) * OC];
#pragma unroll
          for (int q = 0; q < OC / 4; ++q) {
            float4 w4 = wv[q];
            acc[4 * q + 0] = fmaf(w4.x, val, acc[4 * q + 0]);
            acc[4 * q + 1] = fmaf(w4.y, val, acc[4 * q + 1]);
            acc[4 * q + 2] = fmaf(w4.z, val, acc[4 * q + 2]);
            acc[4 * q + 3] = fmaf(w4.w, val, acc[4 * q + 3]);
          }
        }
    }
  }

  float* op = out + (size_t)b * COUT * HW + (size_t)obase * HW + (size_t)yi * W + xi;
#pragma unroll
  for (int o = 0; o < OC; ++o) op[(size_t)o * HW] = fmaxf(acc[o], 0.f);
}

// 2x2 stride-2 max pool.
__global__ void maxpool2_kernel(const float* __restrict__ in, float* __restrict__ out,
                                int B, int C, int H, int W) {
  int Ho = H / 2, Wo = W / 2;
  int gid = blockIdx.x * blockDim.x + threadIdx.x;
  int total = B * C * Ho * Wo;
  if (gid >= total) return;
  int x = gid % Wo;
  int t = gid / Wo;
  int y = t % Ho; t /= Ho;
  int c = t % C;
  int b = t / C;
  const float* p = in + ((size_t)(b * C + c) * H + 2 * y) * W + 2 * x;
  out[gid] = fmaxf(fmaxf(p[0], p[1]), fmaxf(p[W], p[W + 1]));
}

// Adaptive avg pool 24->3 (8x8 bins) + fc(576->10). Block per batch.
__global__ void poolfc_kernel(const float* __restrict__ h,   // [B,64,24,24]
                              const float* __restrict__ wfc, // [10,576]
                              const float* __restrict__ bfc, // [10]
                              float* __restrict__ out) {     // [B,10]
  __shared__ float feat[576];
  int b = blockIdx.x;
  int f = threadIdx.x; // 576 threads
  int c = f / 9, ij = f % 9, i = ij / 3, j = ij % 3;
  const float* p = h + ((size_t)(b * 64 + c) * 24 + i * 8) * 24 + j * 8;
  float s = 0.f;
#pragma unroll
  for (int r = 0; r < 8; ++r)
#pragma unroll
    for (int q = 0; q < 8; ++q)
      s += p[r * 24 + q];
  feat[f] = s * (1.f / 64.f);
  __syncthreads();
  if (f < 10) {
    float acc = bfc[f];
    const float* wp = wfc + f * 576;
    for (int t = 0; t < 576; ++t) acc = fmaf(wp[t], feat[t], acc);
    out[b * 10 + f] = acc;
  }
}

extern "C" void kernel_launch(void* const* d_in, const int* in_sizes, int n_in,
                              void* d_out, int out_size, void* d_ws, size_t ws_size,
                              hipStream_t stream) {
  const float* x      = (const float*)d_in[0];
  const float* w_off1 = (const float*)d_in[1];
  const float* b_off1 = (const float*)d_in[2];
  const float* w1     = (const float*)d_in[3];
  const float* b1     = (const float*)d_in[4];
  const float* w_off2 = (const float*)d_in[5];
  const float* b_off2 = (const float*)d_in[6];
  const float* w2     = (const float*)d_in[7];
  const float* b2     = (const float*)d_in[8];
  const float* w_off3 = (const float*)d_in[9];
  const float* b_off3 = (const float*)d_in[10];
  const float* w3     = (const float*)d_in[11];
  const float* b3     = (const float*)d_in[12];
  const float* w_fc   = (const float*)d_in[13];
  const float* b_fc   = (const float*)d_in[14];
  float* out = (float*)d_out;

  char* ws = (char*)d_ws;
  float* A  = (float*)(ws);               // up to 37.75 MB
  float* Bp = (float*)(ws + 37748736);    // up to 9.44 MB
  float* Cp = (float*)(ws + 47185920);    // up to 10.62 MB

  const int thr = 256;

  // ---- Layer 1: fused offset-conv + deform + relu: x[64,1,96,96] -> A[64,16,96,96]
  {
    int total = 64 * 96 * 96;
    dim3 grid((total + thr - 1) / thr, 1);
    deform_kernel<1, 16, 1, true><<<grid, thr, 0, stream>>>(
        x, nullptr, w_off1, b_off1, w1, b1, A, 64, 96, 96);
  }
  // maxpool -> Bp[64,16,48,48]
  {
    int total = 64 * 16 * 48 * 48;
    maxpool2_kernel<<<(total + thr - 1) / thr, thr, 0, stream>>>(A, Bp, 64, 16, 96, 96);
  }

  // ---- Layer 2: offset conv Bp -> Cp[64,18,48,48]
  {
    int total = 64 * 48 * 48;
    dim3 grid((total + thr - 1) / thr, 1);
    conv3x3_all<16, 18, 1><<<grid, thr, 0, stream>>>(Bp, w_off2, b_off2, Cp, 64, 48, 48);
  }
  // deform + relu -> A[64,32,48,48]   (NSPLIT=2 -> acc[16])
  {
    int total = 64 * 48 * 48;
    dim3 grid((total + thr - 1) / thr, 2);
    deform_kernel<16, 32, 2, false><<<grid, thr, 0, stream>>>(
        Bp, Cp, nullptr, nullptr, w2, b2, A, 64, 48, 48);
  }
  // maxpool -> Bp[64,32,24,24]
  {
    int total = 64 * 32 * 24 * 24;
    maxpool2_kernel<<<(total + thr - 1) / thr, thr, 0, stream>>>(A, Bp, 64, 32, 48, 48);
  }

  // ---- Layer 3: offset conv Bp -> Cp[64,18,24,24]   (NSPLIT=3 -> 432 blocks)
  {
    int total = 64 * 24 * 24;
    dim3 grid((total + thr - 1) / thr, 3);
    conv3x3_all<32, 18, 3><<<grid, thr, 0, stream>>>(Bp, w_off3, b_off3, Cp, 64, 24, 24);
  }
  // deform + relu -> A[64,64,24,24]   (NSPLIT=8 -> acc[8], 1152 blocks)
  {
    int total = 64 * 24 * 24;
    dim3 grid((total + thr - 1) / thr, 8);
    deform_kernel<32, 64, 8, false><<<grid, thr, 0, stream>>>(
        Bp, Cp, nullptr, nullptr, w3, b3, A, 64, 24, 24);
  }

  // ---- avgpool(3x3) + fc -> out[64,10]
  poolfc_kernel<<<64, 576, 0, stream>>>(A, w_fc, b_fc, out);
}